// Round 14
// baseline (182.965 us; speedup 1.0000x reference)
//
#include <hip/hip_runtime.h>
#include <stdint.h>

// ---------- types ----------
typedef __bf16 bf16x8 __attribute__((ext_vector_type(8)));
typedef float  f32x4  __attribute__((ext_vector_type(4)));
typedef float  f32x16 __attribute__((ext_vector_type(16)));
typedef unsigned short u16x4 __attribute__((ext_vector_type(4)));

#define MFMA16(a,b,c) __builtin_amdgcn_mfma_f32_16x16x32_bf16((a),(b),(c),0,0,0)
#define MFMA32(a,b,c) __builtin_amdgcn_mfma_f32_32x32x16_bf16((a),(b),(c),0,0,0)

constexpr int Bc  = 4;
constexpr int Tc  = 2048;
constexpr int Dc  = 768;
constexpr int Hc  = 12;
constexpr int NTOK = Bc * Tc;        // 8192
constexpr int QKV_N = 3 * Dc;        // 2304 (gemm1 output columns)
constexpr int QK_LD = 2 * Dc;        // 1536 (QK-only buffer stride)
constexpr int H4 = NTOK * Dc / 4;    // 1572864 float4 of h
constexpr int W4 = Dc * Dc / 4;      // 147456 float4 per weight

static __device__ __forceinline__ unsigned short f2bf(float f){
  unsigned u = __float_as_uint(f);
  u += 0x7fffu + ((u >> 16) & 1u);   // RNE
  return (unsigned short)(u >> 16);
}

static __device__ __forceinline__ float exp2a(float x){
  float r; asm("v_exp_f32 %0, %1" : "=v"(r) : "v"(x)); return r;
}

static __device__ __forceinline__ float max3f(float a, float b, float c){
  float r; asm("v_max3_f32 %0, %1, %2, %3" : "=v"(r) : "v"(a), "v"(b), "v"(c)); return r;
}

static __device__ __forceinline__ unsigned cvtpk_bf16(float lo, float hi){
  unsigned r; asm("v_cvt_pk_bf16_f32 %0, %1, %2" : "=v"(r) : "v"(lo), "v"(hi)); return r;
}

static __device__ __forceinline__ void gload_lds16(const void* g, void* l){
  __builtin_amdgcn_global_load_lds((__attribute__((address_space(1))) void*)g,
                                   (__attribute__((address_space(3))) void*)l,
                                   16, 0, 0);
}

// ---------- fused f32->bf16 conversion: h + 4 weights in one dispatch ----------
__global__ void prep(const float* __restrict__ h,  const float* __restrict__ Wq,
                     const float* __restrict__ Wk, const float* __restrict__ Wv,
                     const float* __restrict__ Wo,
                     unsigned short* __restrict__ hb,
                     unsigned short* __restrict__ Wqkv,
                     unsigned short* __restrict__ Wob, float qscale){
  const int idx = blockIdx.x * blockDim.x + threadIdx.x;
  const float* src; ushort4* dst; float sc = 1.0f; int r;
  if (idx < H4){
    src = h; dst = reinterpret_cast<ushort4*>(hb); r = idx;
  } else {
    const int j = idx - H4;
    const int y = j / W4;
    r = j - y * W4;
    if (y == 0){ src = Wq; sc = qscale; } else if (y == 1){ src = Wk; }
    else if (y == 2){ src = Wv; } else { src = Wo; }
    dst = (y == 3) ? reinterpret_cast<ushort4*>(Wob)
                   : reinterpret_cast<ushort4*>(Wqkv) + (size_t)y * W4;
  }
  float4 v = reinterpret_cast<const float4*>(src)[r];
  ushort4 o;
  o.x = f2bf(v.x * sc); o.y = f2bf(v.y * sc);
  o.z = f2bf(v.z * sc); o.w = f2bf(v.w * sc);
  dst[r] = o;
}

// ---------- mask expansion with layout auto-detection ----------
__global__ void expand_mask(const unsigned* __restrict__ raw, int* __restrict__ out, int n){
  __shared__ int sInt, sFlt;
  int t = threadIdx.x;
  if (t == 0){ sInt = 1; sFlt = 1; }
  __syncthreads();
  int okI = 1, okF = 1;
  for (int i = t; i < n/4; i += blockDim.x){
    unsigned u = raw[i];
    okI &= (u <= 1u);
    okF &= (u == 0u || u == 0x3f800000u);
  }
  if (!okI) atomicAnd(&sInt, 0);
  if (!okF) atomicAnd(&sFlt, 0);
  __syncthreads();
  if (sInt || sFlt){
    for (int i = t; i < n; i += blockDim.x) out[i] = (raw[i] != 0u);
  } else {
    const unsigned char* rb = (const unsigned char*)raw;
    for (int i = t; i < n; i += blockDim.x) out[i] = (rb[i] != 0);
  }
}

// ---------- gemm1: h @ Wqkv^T, BK=64, XOR-swizzled LDS, XCD swizzle ----------
// C cols [0,1536)   -> QKt[tok][col]
// C cols [1536,2304)-> VtG[(b*H+h)*64+d][tok] (transposed, 8B packed stores)
__global__ __launch_bounds__(256) void gemm_qkv(const unsigned short* __restrict__ A,
                                                const unsigned short* __restrict__ Bm,
                                                unsigned short* __restrict__ QKt,
                                                unsigned short* __restrict__ VtG,
                                                int M, int N, int K){
  __shared__ unsigned short As[128*64];
  __shared__ unsigned short Bs[128*64];
  const int t = threadIdx.x;
  const int w = t >> 6, l = t & 63;
  const int wr = w >> 1, wc = w & 1;
  // bijective XCD swizzle over 1152 blocks (1152%8==0): row-tile grouping
  const int lin = blockIdx.y * gridDim.x + blockIdx.x;   // 0..1151
  const int swz = (lin & 7) * 144 + (lin >> 3);
  const int bxs = swz % 18, bys = swz / 18;
  const int br = bys * 128, bc = bxs * 128;

  f32x4 acc[4][4];
  const f32x4 fz = {0.f,0.f,0.f,0.f};
  #pragma unroll
  for (int m=0;m<4;m++)
    #pragma unroll
    for (int n=0;n<4;n++) acc[m][n] = fz;

  const int srow = l >> 3;             // 0..7
  const int scol = (l & 7) ^ srow;     // source 16B-unit (pre-swizzle, rule #21)
  const int fr = l & 15;
  const int fu = l >> 4;               // 0..3 fragment 16B-unit

  for (int k0 = 0; k0 < K; k0 += 64){
    #pragma unroll
    for (int i = 0; i < 4; ++i){
      const int rb = w*32 + i*8;
      gload_lds16(A  + (size_t)(br + rb + srow)*K + k0 + scol*8, &As[rb*64]);
      gload_lds16(Bm + (size_t)(bc + rb + srow)*K + k0 + scol*8, &Bs[rb*64]);
    }
    __syncthreads();
    bf16x8 a[2][4], b[2][4];
    #pragma unroll
    for (int ks=0; ks<2; ks++){
      #pragma unroll
      for (int m=0;m<4;m++){
        const int row = wr*64 + m*16 + fr;
        a[ks][m] = *reinterpret_cast<const bf16x8*>(
            &As[row*64 + (((ks*4+fu) ^ (row&7))*8)]);
      }
      #pragma unroll
      for (int n=0;n<4;n++){
        const int row = wc*64 + n*16 + fr;
        b[ks][n] = *reinterpret_cast<const bf16x8*>(
            &Bs[row*64 + (((ks*4+fu) ^ (row&7))*8)]);
      }
    }
    #pragma unroll
    for (int ks=0; ks<2; ks++)
      #pragma unroll
      for (int m=0;m<4;m++)
        #pragma unroll
        for (int n=0;n<4;n++)
          acc[m][n] = MFMA16(a[ks][m], b[ks][n], acc[m][n]);
    __syncthreads();
  }

  const int orow0 = br + wr*64 + (l >> 4)*4;
  const int ocol0 = bc + wc*64 + (l & 15);
  if (bc >= QK_LD){
    // V region: write transposed into VtG, 4 consecutive tokens per 8B store
    #pragma unroll
    for (int m=0;m<4;m++){
      const int orow = orow0 + m*16;
      const int bb = orow >> 11, tok = orow & 2047;
      #pragma unroll
      for (int n=0;n<4;n++){
        const int cc = ocol0 + n*16 - QK_LD;   // 0..767
        const int hh = cc >> 6, dd = cc & 63;
        ushort4 o;
        o.x = f2bf(acc[m][n][0]); o.y = f2bf(acc[m][n][1]);
        o.z = f2bf(acc[m][n][2]); o.w = f2bf(acc[m][n][3]);
        *reinterpret_cast<ushort4*>(
            &VtG[((size_t)((bb*Hc + hh)*64 + dd))*Tc + tok]) = o;
      }
    }
  } else {
    #pragma unroll
    for (int m=0;m<4;m++)
      #pragma unroll
      for (int n=0;n<4;n++)
        #pragma unroll
        for (int r=0;r<4;r++)
          QKt[(size_t)(orow0 + m*16 + r) * QK_LD + (ocol0 + n*16)] =
              f2bf(acc[m][n][r]);
  }
}

// ---------- bf16 NT GEMM 64x128 (out-proj, f32 out) + XCD swizzle ----------
__global__ __launch_bounds__(256) void gemm_bt64(const unsigned short* __restrict__ A,
                                                 const unsigned short* __restrict__ Bm,
                                                 float* __restrict__ C,
                                                 int M, int N, int K){
  __shared__ unsigned short As[64*32];
  __shared__ unsigned short Bs[128*32];
  const int t = threadIdx.x;
  const int w = t >> 6, l = t & 63;
  const int wr = w >> 1, wc = w & 1;
  const int lin = blockIdx.y * gridDim.x + blockIdx.x;   // 0..767
  const int swz = (lin & 7) * 96 + (lin >> 3);
  const int bxs = swz % 6, bys = swz / 6;
  const int br = bys * 64, bc = bxs * 128;

  f32x4 acc[2][4];
  const f32x4 fz = {0.f,0.f,0.f,0.f};
  #pragma unroll
  for (int m=0;m<2;m++)
    #pragma unroll
    for (int n=0;n<4;n++) acc[m][n] = fz;

  const int lrow = l >> 2;
  const int lk   = (l & 3) * 8;
  const int fr   = l & 15;
  const int fk   = (l >> 4) * 8;

  for (int k0 = 0; k0 < K; k0 += 32){
    gload_lds16(A + (size_t)(br + w*16 + lrow)*K + k0 + lk, &As[(w*16)*32]);
    #pragma unroll
    for (int it = 0; it < 2; ++it){
      const int rb = it*64 + w*16;
      gload_lds16(Bm + (size_t)(bc + rb + lrow)*K + k0 + lk, &Bs[rb*32]);
    }
    __syncthreads();
    bf16x8 a[2], b[4];
    #pragma unroll
    for (int m=0;m<2;m++)
      a[m] = *reinterpret_cast<const bf16x8*>(&As[(wr*32 + m*16 + fr)*32 + fk]);
    #pragma unroll
    for (int n=0;n<4;n++)
      b[n] = *reinterpret_cast<const bf16x8*>(&Bs[(wc*64 + n*16 + fr)*32 + fk]);
    #pragma unroll
    for (int m=0;m<2;m++)
      #pragma unroll
      for (int n=0;n<4;n++)
        acc[m][n] = MFMA16(a[m], b[n], acc[m][n]);
    __syncthreads();
  }

  const int orow0 = br + wr*32 + (l >> 4)*4;
  const int ocol0 = bc + wc*64 + (l & 15);
  #pragma unroll
  for (int m=0;m<2;m++)
    #pragma unroll
    for (int n=0;n<4;n++)
      #pragma unroll
      for (int r=0;r<4;r++)
        C[(size_t)(orow0 + m*16 + r) * N + (ocol0 + n*16)] = acc[m][n][r];
}

// ---------- flash attention: 32x32 MFMA, software-pipelined QK(c+1) ----------
// 3 LDS buffers. Per iter c: stage(c+2) -> max(c) -> QK(c+1) [MFMA under
// softmax VALU shadow] -> exp/cvtpk(c) -> PV(c) -> barrier.
// Buffers touched in iter c: PV reads c%3, QK reads (c+1)%3, stage writes
// (c+2)%3 — pairwise distinct; barrier+vmcnt(0) seals each iteration.
__global__ __launch_bounds__(256, 3) void attn(const unsigned short* __restrict__ QKt,
                                               const unsigned short* __restrict__ VtG,
                                               const int* __restrict__ mask,
                                               unsigned short* __restrict__ AO){
  __shared__ unsigned short Ks[3][64*64];  // K chunk, source-swizzled (16B units: c ^= row&7)
  __shared__ unsigned short Vs[3][64*64];  // V^T chunk [d][key], same source swizzle
  __shared__ float Ms[3][64];              // additive key-mask bias

  const int t = threadIdx.x, w = t >> 6, l = t & 63;
  const int lin = blockIdx.y * gridDim.x + blockIdx.x;   // 0..767
  const int swz = (lin & 7) * 96 + (lin >> 3);
  const int qt  = swz & 15;
  const int bh  = swz >> 4;
  const int b  = bh / Hc, h = bh - b * Hc;
  const int lq = l & 31, hi = l >> 5;
  const int q0w = qt * 128 + w * 32;

  const size_t tokbase = (size_t)b * Tc;
  const unsigned short* Qp = QKt + (tokbase + q0w) * (size_t)QK_LD + h*64;
  const unsigned short* Kbase = QKt + tokbase * (size_t)QK_LD + h*64 + 768;
  const unsigned short* VtB = VtG + (size_t)(bh*64) * Tc;
  const int* bm = mask + b * Tc;

  bf16x8 qa[4];
  #pragma unroll
  for (int s=0; s<4; s++)
    qa[s] = *reinterpret_cast<const bf16x8*>(
        Qp + (size_t)lq*QK_LD + s*16 + hi*8);

  unsigned bits = 0;
  if (w == 0){
    #pragma unroll
    for (int cc = 0; cc < 32; ++cc)
      bits |= (unsigned)(bm[cc*64 + l] != 0) << cc;
  }

  f32x16 accO[2];
  #pragma unroll
  for (int dg=0; dg<2; dg++)
    #pragma unroll
    for (int r=0; r<16; r++) accO[dg][r] = 0.f;
  float mrow = -1e30f, lsum = 0.f;

  const int srow = l >> 3, scol = (l & 7) ^ (l >> 3);   // source swizzle
  auto stage = [&](int c){
    const int key0 = c * 64, buf = c % 3;
    #pragma unroll
    for (int i=0; i<2; i++){
      const int rb = w*16 + i*8;      // K rows
      gload_lds16(Kbase + (size_t)(key0 + rb + srow)*QK_LD + scol*8,
                  &Ks[buf][rb*64]);
    }
    #pragma unroll
    for (int i=0; i<2; i++){
      const int rb = (w*2 + i)*8;     // V^T rows (d)
      gload_lds16(VtB + (size_t)(rb + srow)*Tc + key0 + scol*8,
                  &Vs[buf][rb*64]);
    }
  };

  // QK^T for chunk c into S (C-init = mask bias); reads Ks[c%3], Ms[c%3]
  auto qk = [&](int c, f32x16 (&S)[2]){
    const int buf = c % 3;
    #pragma unroll
    for (int g=0; g<2; g++){
      union { f32x4 q[4]; f32x16 v; } mi;
      #pragma unroll
      for (int m=0; m<4; m++)
        mi.q[m] = *reinterpret_cast<const f32x4*>(&Ms[buf][g*32 + m*8 + hi*4]);
      S[g] = mi.v;
      #pragma unroll
      for (int s=0; s<4; s++){
        const int row = g*32 + lq;
        bf16x8 kf = *reinterpret_cast<const bf16x8*>(
            &Ks[buf][row*64 + (((2*s + hi) ^ (row&7))*8)]);
        S[g] = MFMA32(kf, qa[s], S[g]);
      }
    }
  };

  f32x16 SA[2], SB[2];

  // ---- prologue: stage chunks 0,1; Ms[0..1]; compute S(0)
  stage(0); stage(1);
  if (w == 0){
    Ms[0][l] = (bits & 1u) ? -1e9f : 0.f;
    Ms[1][l] = (bits & 2u) ? -1e9f : 0.f;
  }
  asm volatile("s_waitcnt vmcnt(0) lgkmcnt(0)" ::: "memory");
  __builtin_amdgcn_s_barrier();
  asm volatile("" ::: "memory");
  qk(0, SA);

  auto body = [&](int c, f32x16 (&Scur)[2], f32x16 (&Snxt)[2]){
    const int cb = c % 3;
    if (c + 2 < 32) stage(c + 2);

    // ---- max-reduce(c) (short; produces mrow before exp phase)
    {
      float m0 = max3f(Scur[0][0],  Scur[0][1],  Scur[0][2]);
      float m1 = max3f(Scur[0][3],  Scur[0][4],  Scur[0][5]);
      float m2 = max3f(Scur[0][6],  Scur[0][7],  Scur[0][8]);
      float m3 = max3f(Scur[0][9],  Scur[0][10], Scur[0][11]);
      float m4 = max3f(Scur[0][12], Scur[0][13], Scur[0][14]);
      float m5 = max3f(Scur[0][15], Scur[1][0],  Scur[1][1]);
      float m6 = max3f(Scur[1][2],  Scur[1][3],  Scur[1][4]);
      float m7 = max3f(Scur[1][5],  Scur[1][6],  Scur[1][7]);
      float m8 = max3f(Scur[1][8],  Scur[1][9],  Scur[1][10]);
      float m9 = max3f(Scur[1][11], Scur[1][12], Scur[1][13]);
      float ma = fmaxf(Scur[1][14], Scur[1][15]);
      float cm = max3f(max3f(m0,m1,m2), max3f(m3,m4,m5),
                       max3f(max3f(m6,m7,m8), m9, ma));
      cm = fmaxf(cm, __shfl_xor(cm, 32));
      if (!__all(cm <= mrow + 8.0f)){     // defer-max (T13)
        const float nm = fmaxf(mrow, cm);
        const float sc = exp2a(mrow - nm);
        lsum *= sc;
        #pragma unroll
        for (int dg=0; dg<2; dg++)
          #pragma unroll
          for (int r=0; r<16; r++) accO[dg][r] *= sc;
        mrow = nm;
      }
    }

    // ---- QK(c+1): matrix-pipe work issued under the exp/cvtpk VALU shadow
    if (c + 1 < 32) qk(c + 1, Snxt);

    // ---- exp/cvtpk/sum on Scur
    unsigned pk[2][2][4];
    {
      float ps = 0.f;
      #pragma unroll
      for (int g=0; g<2; g++){
        float p[16];
        #pragma unroll
        for (int r=0; r<16; r++) p[r] = exp2a(Scur[g][r] - mrow);
        float t0 = (p[0]+p[1]) + (p[2]+p[3]);
        float t1 = (p[4]+p[5]) + (p[6]+p[7]);
        float t2 = (p[8]+p[9]) + (p[10]+p[11]);
        float t3 = (p[12]+p[13]) + (p[14]+p[15]);
        ps += (t0+t1) + (t2+t3);
        #pragma unroll
        for (int ss=0; ss<2; ss++)
          #pragma unroll
          for (int j2=0; j2<4; j2++)
            pk[g][ss][j2] = cvtpk_bf16(p[ss*8 + 2*j2], p[ss*8 + 2*j2 + 1]);
      }
      ps += __shfl_xor(ps, 32);
      lsum += ps;
    }

    // ---- PV(c)
    __builtin_amdgcn_s_setprio(1);
    #pragma unroll
    for (int g=0; g<2; g++){
      #pragma unroll
      for (int ss=0; ss<2; ss++){
        union { unsigned u[4]; bf16x8 v; } pb;
        pb.u[0] = pk[g][ss][0]; pb.u[1] = pk[g][ss][1];
        pb.u[2] = pk[g][ss][2]; pb.u[3] = pk[g][ss][3];
        const int u0 = 4*g + 2*ss;
        #pragma unroll
        for (int dg=0; dg<2; dg++){
          const int d = dg*32 + lq;
          union { u16x4 h[2]; bf16x8 v; } va;
          va.h[0] = *reinterpret_cast<const u16x4*>(
              &Vs[cb][d*64 + ((u0     ^ (d&7))*8) + hi*4]);
          va.h[1] = *reinterpret_cast<const u16x4*>(
              &Vs[cb][d*64 + (((u0+1) ^ (d&7))*8) + hi*4]);
          accO[dg] = MFMA32(va.v, pb.v, accO[dg]);
        }
      }
    }
    __builtin_amdgcn_s_setprio(0);

    // ---- Ms(c+2) from register bits (no VMEM)
    if (w == 0 && c + 2 < 32)
      Ms[(c+2)%3][l] = ((bits >> (c+2)) & 1u) ? -1e9f : 0.f;

    if (c < 31){
      asm volatile("s_waitcnt vmcnt(0) lgkmcnt(0)" ::: "memory");
      __builtin_amdgcn_s_barrier();
      asm volatile("" ::: "memory");
    }
  };

  #pragma unroll 1
  for (int cc = 0; cc < 16; ++cc){
    body(2*cc,     SA, SB);
    body(2*cc + 1, SB, SA);
  }

  // ---- epilogue: normalize, zero q-padded rows, 8B stores
  {
    const int qrow = q0w + lq;
    const int qm = bm[qrow];
    const float inv = (qm || lsum <= 0.f) ? 0.f : 1.f / lsum;
    #pragma unroll
    for (int dg=0; dg<2; dg++)
      #pragma unroll
      for (int m=0; m<4; m++){
        ushort4 o;
        o.x = f2bf(accO[dg][4*m+0] * inv);
        o.y = f2bf(accO[dg][4*m+1] * inv);
        o.z = f2bf(accO[dg][4*m+2] * inv);
        o.w = f2bf(accO[dg][4*m+3] * inv);
        *reinterpret_cast<ushort4*>(
            &AO[(tokbase + qrow) * (size_t)Dc + h*64 + dg*32 + m*8 + hi*4]) = o;
      }
  }
}

// ---------- launch ----------
extern "C" void kernel_launch(void* const* d_in, const int* in_sizes, int n_in,
                              void* d_out, int out_size, void* d_ws, size_t ws_size,
                              hipStream_t stream){
  const float* h    = (const float*)d_in[0];
  const unsigned* m = (const unsigned*)d_in[1];
  const float* Wq   = (const float*)d_in[2];
  const float* Wk   = (const float*)d_in[3];
  const float* Wv   = (const float*)d_in[4];
  const float* Wo   = (const float*)d_in[5];
  float* out        = (float*)d_out;

  unsigned short* hb   = (unsigned short*)d_ws;       // 8192*768
  unsigned short* Wqkv = hb   + (size_t)NTOK * Dc;    // 2304*768
  unsigned short* Wob  = Wqkv + (size_t)QKV_N * Dc;   // 768*768
  unsigned short* QKt  = Wob  + (size_t)Dc * Dc;      // 8192*1536 (Q|K)
  unsigned short* VtG  = QKt  + (size_t)NTOK * QK_LD; // 48*64 x 2048 (V^T)
  unsigned short* AO   = VtG  + (size_t)NTOK * Dc;    // 8192*768
  int* mexp            = (int*)(AO + (size_t)NTOK * Dc);

  const size_t need = ((size_t)NTOK*Dc + (size_t)QKV_N*Dc + (size_t)Dc*Dc +
                       (size_t)NTOK*QK_LD + (size_t)NTOK*Dc + (size_t)NTOK*Dc) * 2
                      + (size_t)NTOK*4;
  if (ws_size < need) return;

  // fused conversions: h + Wq(scaled by log2e/8) + Wk + Wv + Wo
  prep<<<(H4 + 4*W4 + 255)/256, 256, 0, stream>>>(
      h, Wq, Wk, Wv, Wo, hb, Wqkv, Wob, 0.125f*1.44269504f);
  expand_mask<<<1, 256, 0, stream>>>(m, mexp, NTOK);

  // fused QKV projection (BK=64); V written transposed straight into VtG
  gemm_qkv<<<dim3(QKV_N/128, NTOK/128), 256, 0, stream>>>(
      hb, Wqkv, QKt, VtG, NTOK, QKV_N, Dc);

  attn<<<dim3(16, Bc*Hc), 256, 0, stream>>>(QKt, VtG, mexp, AO);

  gemm_bt64<<<dim3(Dc/128, NTOK/64), 256, 0, stream>>>(
      AO, Wob, out, NTOK, Dc, Dc);
}

// Round 17
// 162.430 us; speedup vs baseline: 1.1264x; 1.1264x over previous
//
#include <hip/hip_runtime.h>
#include <stdint.h>

// ---------- types ----------
typedef __bf16 bf16x8 __attribute__((ext_vector_type(8)));
typedef float  f32x4  __attribute__((ext_vector_type(4)));
typedef float  f32x16 __attribute__((ext_vector_type(16)));
typedef unsigned short u16x4 __attribute__((ext_vector_type(4)));

#define MFMA16(a,b,c) __builtin_amdgcn_mfma_f32_16x16x32_bf16((a),(b),(c),0,0,0)
#define MFMA32(a,b,c) __builtin_amdgcn_mfma_f32_32x32x16_bf16((a),(b),(c),0,0,0)

constexpr int Bc  = 4;
constexpr int Tc  = 2048;
constexpr int Dc  = 768;
constexpr int Hc  = 12;
constexpr int NTOK = Bc * Tc;        // 8192
constexpr int QKV_N = 3 * Dc;        // 2304 (gemm1 output columns)
constexpr int QK_LD = 2 * Dc;        // 1536 (QK-only buffer stride)
constexpr int H4 = NTOK * Dc / 4;    // 1572864 float4 of h
constexpr int W4 = Dc * Dc / 4;      // 147456 float4 per weight

static __device__ __forceinline__ unsigned short f2bf(float f){
  unsigned u = __float_as_uint(f);
  u += 0x7fffu + ((u >> 16) & 1u);   // RNE
  return (unsigned short)(u >> 16);
}

static __device__ __forceinline__ float exp2a(float x){
  float r; asm("v_exp_f32 %0, %1" : "=v"(r) : "v"(x)); return r;
}

static __device__ __forceinline__ float max3f(float a, float b, float c){
  float r; asm("v_max3_f32 %0, %1, %2, %3" : "=v"(r) : "v"(a), "v"(b), "v"(c)); return r;
}

static __device__ __forceinline__ unsigned cvtpk_bf16(float lo, float hi){
  unsigned r; asm("v_cvt_pk_bf16_f32 %0, %1, %2" : "=v"(r) : "v"(lo), "v"(hi)); return r;
}

static __device__ __forceinline__ void gload_lds16(const void* g, void* l){
  __builtin_amdgcn_global_load_lds((__attribute__((address_space(1))) void*)g,
                                   (__attribute__((address_space(3))) void*)l,
                                   16, 0, 0);
}

// ---------- fused prep: h + 4 weight conversions + mask expansion ----------
// Last block (blockIdx.x == gridDim.x-1) does mask expansion; others convert.
__global__ void prep(const float* __restrict__ h,  const float* __restrict__ Wq,
                     const float* __restrict__ Wk, const float* __restrict__ Wv,
                     const float* __restrict__ Wo,
                     unsigned short* __restrict__ hb,
                     unsigned short* __restrict__ Wqkv,
                     unsigned short* __restrict__ Wob, float qscale,
                     const unsigned* __restrict__ raw, int* __restrict__ mout){
  if (blockIdx.x == gridDim.x - 1){
    // ---- mask expansion with layout auto-detection (single block)
    __shared__ int sInt, sFlt;
    const int t = threadIdx.x, n = NTOK;
    if (t == 0){ sInt = 1; sFlt = 1; }
    __syncthreads();
    int okI = 1, okF = 1;
    for (int i = t; i < n/4; i += blockDim.x){
      unsigned u = raw[i];
      okI &= (u <= 1u);
      okF &= (u == 0u || u == 0x3f800000u);
    }
    if (!okI) atomicAnd(&sInt, 0);
    if (!okF) atomicAnd(&sFlt, 0);
    __syncthreads();
    if (sInt || sFlt){
      for (int i = t; i < n; i += blockDim.x) mout[i] = (raw[i] != 0u);
    } else {
      const unsigned char* rb = (const unsigned char*)raw;
      for (int i = t; i < n; i += blockDim.x) mout[i] = (rb[i] != 0);
    }
    return;
  }
  const int idx = blockIdx.x * blockDim.x + threadIdx.x;
  const float* src; ushort4* dst; float sc = 1.0f; int r;
  if (idx < H4){
    src = h; dst = reinterpret_cast<ushort4*>(hb); r = idx;
  } else {
    const int j = idx - H4;
    const int y = j / W4;
    r = j - y * W4;
    if (y == 0){ src = Wq; sc = qscale; } else if (y == 1){ src = Wk; }
    else if (y == 2){ src = Wv; } else { src = Wo; }
    dst = (y == 3) ? reinterpret_cast<ushort4*>(Wob)
                   : reinterpret_cast<ushort4*>(Wqkv) + (size_t)y * W4;
  }
  float4 v = reinterpret_cast<const float4*>(src)[r];
  ushort4 o;
  o.x = f2bf(v.x * sc); o.y = f2bf(v.y * sc);
  o.z = f2bf(v.z * sc); o.w = f2bf(v.w * sc);
  dst[r] = o;
}

// ---------- gemm1: h @ Wqkv^T, BK=64, XOR-swizzled LDS, XCD swizzle ----------
// C cols [0,1536)   -> QKt[tok][col]
// C cols [1536,2304)-> VtG[(b*H+h)*64+d][tok] (transposed, 8B packed stores)
__global__ __launch_bounds__(256) void gemm_qkv(const unsigned short* __restrict__ A,
                                                const unsigned short* __restrict__ Bm,
                                                unsigned short* __restrict__ QKt,
                                                unsigned short* __restrict__ VtG,
                                                int M, int N, int K){
  __shared__ unsigned short As[128*64];
  __shared__ unsigned short Bs[128*64];
  const int t = threadIdx.x;
  const int w = t >> 6, l = t & 63;
  const int wr = w >> 1, wc = w & 1;
  // bijective XCD swizzle over 1152 blocks (1152%8==0): row-tile grouping
  const int lin = blockIdx.y * gridDim.x + blockIdx.x;   // 0..1151
  const int swz = (lin & 7) * 144 + (lin >> 3);
  const int bxs = swz % 18, bys = swz / 18;
  const int br = bys * 128, bc = bxs * 128;

  f32x4 acc[4][4];
  const f32x4 fz = {0.f,0.f,0.f,0.f};
  #pragma unroll
  for (int m=0;m<4;m++)
    #pragma unroll
    for (int n=0;n<4;n++) acc[m][n] = fz;

  const int srow = l >> 3;             // 0..7
  const int scol = (l & 7) ^ srow;     // source 16B-unit (pre-swizzle, rule #21)
  const int fr = l & 15;
  const int fu = l >> 4;               // 0..3 fragment 16B-unit

  for (int k0 = 0; k0 < K; k0 += 64){
    #pragma unroll
    for (int i = 0; i < 4; ++i){
      const int rb = w*32 + i*8;
      gload_lds16(A  + (size_t)(br + rb + srow)*K + k0 + scol*8, &As[rb*64]);
      gload_lds16(Bm + (size_t)(bc + rb + srow)*K + k0 + scol*8, &Bs[rb*64]);
    }
    __syncthreads();
    bf16x8 a[2][4], b[2][4];
    #pragma unroll
    for (int ks=0; ks<2; ks++){
      #pragma unroll
      for (int m=0;m<4;m++){
        const int row = wr*64 + m*16 + fr;
        a[ks][m] = *reinterpret_cast<const bf16x8*>(
            &As[row*64 + (((ks*4+fu) ^ (row&7))*8)]);
      }
      #pragma unroll
      for (int n=0;n<4;n++){
        const int row = wc*64 + n*16 + fr;
        b[ks][n] = *reinterpret_cast<const bf16x8*>(
            &Bs[row*64 + (((ks*4+fu) ^ (row&7))*8)]);
      }
    }
    #pragma unroll
    for (int ks=0; ks<2; ks++)
      #pragma unroll
      for (int m=0;m<4;m++)
        #pragma unroll
        for (int n=0;n<4;n++)
          acc[m][n] = MFMA16(a[ks][m], b[ks][n], acc[m][n]);
    __syncthreads();
  }

  const int orow0 = br + wr*64 + (l >> 4)*4;
  const int ocol0 = bc + wc*64 + (l & 15);
  if (bc >= QK_LD){
    // V region: write transposed into VtG, 4 consecutive tokens per 8B store
    #pragma unroll
    for (int m=0;m<4;m++){
      const int orow = orow0 + m*16;
      const int bb = orow >> 11, tok = orow & 2047;
      #pragma unroll
      for (int n=0;n<4;n++){
        const int cc = ocol0 + n*16 - QK_LD;   // 0..767
        const int hh = cc >> 6, dd = cc & 63;
        ushort4 o;
        o.x = f2bf(acc[m][n][0]); o.y = f2bf(acc[m][n][1]);
        o.z = f2bf(acc[m][n][2]); o.w = f2bf(acc[m][n][3]);
        *reinterpret_cast<ushort4*>(
            &VtG[((size_t)((bb*Hc + hh)*64 + dd))*Tc + tok]) = o;
      }
    }
  } else {
    #pragma unroll
    for (int m=0;m<4;m++)
      #pragma unroll
      for (int n=0;n<4;n++)
        #pragma unroll
        for (int r=0;r<4;r++)
          QKt[(size_t)(orow0 + m*16 + r) * QK_LD + (ocol0 + n*16)] =
              f2bf(acc[m][n][r]);
  }
}

// ---------- bf16 NT GEMM 64x128, BK=64, XOR-swizzled LDS (out-proj, f32 out) ----------
__global__ __launch_bounds__(256) void gemm_bt64(const unsigned short* __restrict__ A,
                                                 const unsigned short* __restrict__ Bm,
                                                 float* __restrict__ C,
                                                 int M, int N, int K){
  __shared__ unsigned short As[64*64];
  __shared__ unsigned short Bs[128*64];
  const int t = threadIdx.x;
  const int w = t >> 6, l = t & 63;
  const int wr = w >> 1, wc = w & 1;
  const int lin = blockIdx.y * gridDim.x + blockIdx.x;   // 0..767
  const int swz = (lin & 7) * 96 + (lin >> 3);
  const int bxs = swz % 6, bys = swz / 6;
  const int br = bys * 64, bc = bxs * 128;

  f32x4 acc[2][4];
  const f32x4 fz = {0.f,0.f,0.f,0.f};
  #pragma unroll
  for (int m=0;m<2;m++)
    #pragma unroll
    for (int n=0;n<4;n++) acc[m][n] = fz;

  const int srow = l >> 3;
  const int scol = (l & 7) ^ srow;     // source swizzle (rule #21)
  const int fr = l & 15;
  const int fu = l >> 4;

  for (int k0 = 0; k0 < K; k0 += 64){
    #pragma unroll
    for (int i = 0; i < 2; ++i){       // A: 64 rows
      const int rb = w*16 + i*8;
      gload_lds16(A + (size_t)(br + rb + srow)*K + k0 + scol*8, &As[rb*64]);
    }
    #pragma unroll
    for (int i = 0; i < 4; ++i){       // B: 128 rows
      const int rb = w*32 + i*8;
      gload_lds16(Bm + (size_t)(bc + rb + srow)*K + k0 + scol*8, &Bs[rb*64]);
    }
    __syncthreads();
    bf16x8 a[2][2], b[2][4];
    #pragma unroll
    for (int ks=0; ks<2; ks++){
      #pragma unroll
      for (int m=0;m<2;m++){
        const int row = wr*32 + m*16 + fr;
        a[ks][m] = *reinterpret_cast<const bf16x8*>(
            &As[row*64 + (((ks*4+fu) ^ (row&7))*8)]);
      }
      #pragma unroll
      for (int n=0;n<4;n++){
        const int row = wc*64 + n*16 + fr;
        b[ks][n] = *reinterpret_cast<const bf16x8*>(
            &Bs[row*64 + (((ks*4+fu) ^ (row&7))*8)]);
      }
    }
    #pragma unroll
    for (int ks=0; ks<2; ks++)
      #pragma unroll
      for (int m=0;m<2;m++)
        #pragma unroll
        for (int n=0;n<4;n++)
          acc[m][n] = MFMA16(a[ks][m], b[ks][n], acc[m][n]);
    __syncthreads();
  }

  const int orow0 = br + wr*32 + (l >> 4)*4;
  const int ocol0 = bc + wc*64 + (l & 15);
  #pragma unroll
  for (int m=0;m<2;m++)
    #pragma unroll
    for (int n=0;n<4;n++)
      #pragma unroll
      for (int r=0;r<4;r++)
        C[(size_t)(orow0 + m*16 + r) * N + (ocol0 + n*16)] = acc[m][n][r];
}

// ---------- flash attention: 32x32 MFMA, Q=128/block, 2-buffer, XCD swizzle ----------
// REVERTED to the round-13 verified version (87.4us). Round-14's pipelined
// variant spilled registers (WRITE_SIZE 12.6->23MB scratch traffic) and
// regressed; this structure is declared done.
__global__ __launch_bounds__(256, 3) void attn(const unsigned short* __restrict__ QKt,
                                               const unsigned short* __restrict__ VtG,
                                               const int* __restrict__ mask,
                                               unsigned short* __restrict__ AO){
  __shared__ unsigned short Ks[2][64*64];  // K chunk, source-swizzled (16B units: c ^= row&7)
  __shared__ unsigned short Vs[2][64*64];  // V^T chunk [d][key], same source swizzle
  __shared__ float Ms[2][64];              // additive key-mask bias

  const int t = threadIdx.x, w = t >> 6, l = t & 63;
  const int lin = blockIdx.y * gridDim.x + blockIdx.x;   // 0..767
  const int swz = (lin & 7) * 96 + (lin >> 3);
  const int qt  = swz & 15;
  const int bh  = swz >> 4;
  const int b  = bh / Hc, h = bh - b * Hc;
  const int lq = l & 31, hi = l >> 5;
  const int q0w = qt * 128 + w * 32;

  const size_t tokbase = (size_t)b * Tc;
  const unsigned short* Qp = QKt + (tokbase + q0w) * (size_t)QK_LD + h*64;
  const unsigned short* Kbase = QKt + tokbase * (size_t)QK_LD + h*64 + 768;
  const unsigned short* VtB = VtG + (size_t)(bh*64) * Tc;
  const int* bm = mask + b * Tc;

  bf16x8 qa[4];
  #pragma unroll
  for (int s=0; s<4; s++)
    qa[s] = *reinterpret_cast<const bf16x8*>(
        Qp + (size_t)lq*QK_LD + s*16 + hi*8);

  unsigned bits = 0;
  if (w == 0){
    #pragma unroll
    for (int cc = 0; cc < 32; ++cc)
      bits |= (unsigned)(bm[cc*64 + l] != 0) << cc;
  }

  f32x16 accO[2];
  #pragma unroll
  for (int dg=0; dg<2; dg++)
    #pragma unroll
    for (int r=0; r<16; r++) accO[dg][r] = 0.f;
  float mrow = -1e30f, lsum = 0.f;

  const int srow = l >> 3, scol = (l & 7) ^ (l >> 3);   // source swizzle
  auto stage = [&](int c){
    const int key0 = c * 64, buf = c & 1;
    #pragma unroll
    for (int i=0; i<2; i++){
      const int rb = w*16 + i*8;      // K rows
      gload_lds16(Kbase + (size_t)(key0 + rb + srow)*QK_LD + scol*8,
                  &Ks[buf][rb*64]);
    }
    #pragma unroll
    for (int i=0; i<2; i++){
      const int rb = (w*2 + i)*8;     // V^T rows (d)
      gload_lds16(VtB + (size_t)(rb + srow)*Tc + key0 + scol*8,
                  &Vs[buf][rb*64]);
    }
  };

  stage(0);
  if (w == 0) Ms[0][l] = (bits & 1u) ? -1e9f : 0.f;
  asm volatile("s_waitcnt vmcnt(0) lgkmcnt(0)" ::: "memory");
  __builtin_amdgcn_s_barrier();
  asm volatile("" ::: "memory");

  #pragma unroll 2
  for (int c = 0; c < 32; ++c){
    const int cb = c & 1;

    f32x16 S[2];
    __builtin_amdgcn_s_setprio(1);
    #pragma unroll
    for (int g=0; g<2; g++){
      union { f32x4 q[4]; f32x16 v; } mi;
      #pragma unroll
      for (int m=0; m<4; m++)
        mi.q[m] = *reinterpret_cast<const f32x4*>(&Ms[cb][g*32 + m*8 + hi*4]);
      S[g] = mi.v;
      #pragma unroll
      for (int s=0; s<4; s++){
        const int row = g*32 + lq;
        bf16x8 kf = *reinterpret_cast<const bf16x8*>(
            &Ks[cb][row*64 + (((2*s + hi) ^ (row&7))*8)]);
        S[g] = MFMA32(kf, qa[s], S[g]);
      }
    }
    __builtin_amdgcn_s_setprio(0);

    if (c + 1 < 32) stage(c + 1);

    unsigned pk[2][2][4];
    {
      float m0 = max3f(S[0][0],  S[0][1],  S[0][2]);
      float m1 = max3f(S[0][3],  S[0][4],  S[0][5]);
      float m2 = max3f(S[0][6],  S[0][7],  S[0][8]);
      float m3 = max3f(S[0][9],  S[0][10], S[0][11]);
      float m4 = max3f(S[0][12], S[0][13], S[0][14]);
      float m5 = max3f(S[0][15], S[1][0],  S[1][1]);
      float m6 = max3f(S[1][2],  S[1][3],  S[1][4]);
      float m7 = max3f(S[1][5],  S[1][6],  S[1][7]);
      float m8 = max3f(S[1][8],  S[1][9],  S[1][10]);
      float m9 = max3f(S[1][11], S[1][12], S[1][13]);
      float ma = fmaxf(S[1][14], S[1][15]);
      float cm = max3f(max3f(m0,m1,m2), max3f(m3,m4,m5),
                       max3f(max3f(m6,m7,m8), m9, ma));
      cm = fmaxf(cm, __shfl_xor(cm, 32));
      if (!__all(cm <= mrow + 8.0f)){     // defer-max (T13)
        const float nm = fmaxf(mrow, cm);
        const float sc = exp2a(mrow - nm);
        lsum *= sc;
        #pragma unroll
        for (int dg=0; dg<2; dg++)
          #pragma unroll
          for (int r=0; r<16; r++) accO[dg][r] *= sc;
        mrow = nm;
      }
      float ps = 0.f;
      #pragma unroll
      for (int g=0; g<2; g++){
        float p[16];
        #pragma unroll
        for (int r=0; r<16; r++) p[r] = exp2a(S[g][r] - mrow);
        float t0 = (p[0]+p[1]) + (p[2]+p[3]);
        float t1 = (p[4]+p[5]) + (p[6]+p[7]);
        float t2 = (p[8]+p[9]) + (p[10]+p[11]);
        float t3 = (p[12]+p[13]) + (p[14]+p[15]);
        ps += (t0+t1) + (t2+t3);
        #pragma unroll
        for (int ss=0; ss<2; ss++)
          #pragma unroll
          for (int j2=0; j2<4; j2++)
            pk[g][ss][j2] = cvtpk_bf16(p[ss*8 + 2*j2], p[ss*8 + 2*j2 + 1]);
      }
      ps += __shfl_xor(ps, 32);
      lsum += ps;
    }

    __builtin_amdgcn_s_setprio(1);
    #pragma unroll
    for (int g=0; g<2; g++){
      #pragma unroll
      for (int ss=0; ss<2; ss++){
        union { unsigned u[4]; bf16x8 v; } pb;
        pb.u[0] = pk[g][ss][0]; pb.u[1] = pk[g][ss][1];
        pb.u[2] = pk[g][ss][2]; pb.u[3] = pk[g][ss][3];
        const int u0 = 4*g + 2*ss;
        #pragma unroll
        for (int dg=0; dg<2; dg++){
          const int d = dg*32 + lq;
          union { u16x4 h[2]; bf16x8 v; } va;
          va.h[0] = *reinterpret_cast<const u16x4*>(
              &Vs[cb][d*64 + ((u0     ^ (d&7))*8) + hi*4]);
          va.h[1] = *reinterpret_cast<const u16x4*>(
              &Vs[cb][d*64 + (((u0+1) ^ (d&7))*8) + hi*4]);
          accO[dg] = MFMA32(va.v, pb.v, accO[dg]);
        }
      }
    }
    __builtin_amdgcn_s_setprio(0);

    if (w == 0 && c + 1 < 32)
      Ms[cb^1][l] = ((bits >> (c+1)) & 1u) ? -1e9f : 0.f;

    if (c < 31){
      asm volatile("s_waitcnt vmcnt(0) lgkmcnt(0)" ::: "memory");
      __builtin_amdgcn_s_barrier();
      asm volatile("" ::: "memory");
    }
  }

  {
    const int qrow = q0w + lq;
    const int qm = bm[qrow];
    const float inv = (qm || lsum <= 0.f) ? 0.f : 1.f / lsum;
    #pragma unroll
    for (int dg=0; dg<2; dg++)
      #pragma unroll
      for (int m=0; m<4; m++){
        ushort4 o;
        o.x = f2bf(accO[dg][4*m+0] * inv);
        o.y = f2bf(accO[dg][4*m+1] * inv);
        o.z = f2bf(accO[dg][4*m+2] * inv);
        o.w = f2bf(accO[dg][4*m+3] * inv);
        *reinterpret_cast<ushort4*>(
            &AO[(tokbase + qrow) * (size_t)Dc + h*64 + dg*32 + m*8 + hi*4]) = o;
      }
  }
}

// ---------- launch ----------
extern "C" void kernel_launch(void* const* d_in, const int* in_sizes, int n_in,
                              void* d_out, int out_size, void* d_ws, size_t ws_size,
                              hipStream_t stream){
  const float* h    = (const float*)d_in[0];
  const unsigned* m = (const unsigned*)d_in[1];
  const float* Wq   = (const float*)d_in[2];
  const float* Wk   = (const float*)d_in[3];
  const float* Wv   = (const float*)d_in[4];
  const float* Wo   = (const float*)d_in[5];
  float* out        = (float*)d_out;

  unsigned short* hb   = (unsigned short*)d_ws;       // 8192*768
  unsigned short* Wqkv = hb   + (size_t)NTOK * Dc;    // 2304*768
  unsigned short* Wob  = Wqkv + (size_t)QKV_N * Dc;   // 768*768
  unsigned short* QKt  = Wob  + (size_t)Dc * Dc;      // 8192*1536 (Q|K)
  unsigned short* VtG  = QKt  + (size_t)NTOK * QK_LD; // 48*64 x 2048 (V^T)
  unsigned short* AO   = VtG  + (size_t)NTOK * Dc;    // 8192*768
  int* mexp            = (int*)(AO + (size_t)NTOK * Dc);

  const size_t need = ((size_t)NTOK*Dc + (size_t)QKV_N*Dc + (size_t)Dc*Dc +
                       (size_t)NTOK*QK_LD + (size_t)NTOK*Dc + (size_t)NTOK*Dc) * 2
                      + (size_t)NTOK*4;
  if (ws_size < need) return;

  // fused conversions (h + weights) + mask expansion (last block)
  prep<<<(H4 + 4*W4)/256 + 1, 256, 0, stream>>>(
      h, Wq, Wk, Wv, Wo, hb, Wqkv, Wob, 0.125f*1.44269504f, m, mexp);

  // fused QKV projection (BK=64); V written transposed straight into VtG
  gemm_qkv<<<dim3(QKV_N/128, NTOK/128), 256, 0, stream>>>(
      hb, Wqkv, QKt, VtG, NTOK, QKV_N, Dc);

  attn<<<dim3(16, Bc*Hc), 256, 0, stream>>>(QKt, VtG, mexp, AO);

  gemm_bt64<<<dim3(Dc/128, NTOK/64), 256, 0, stream>>>(
      AO, Wob, out, NTOK, Dc, Dc);
}